// Round 8
// baseline (86.994 us; speedup 1.0000x reference)
//
#include <hip/hip_runtime.h>
#include <math.h>

#define N_HARM 80
#define HOP 240
#define NUM_NOTES 8
#define BLK 256
#define NROWS 4   // amp rows staged per block: i0 spans <=3 values, +1 for i1

#define TWO_PI_D     6.283185307179586476925286766559
#define INV_TWO_PI_D 0.15915494309189533576888376337251

// exact for x in [0, 2^23): result in [0,1)
static __device__ __forceinline__ float fract1(float x) { return x - floorf(x); }

// Kernel 1: per-batch setup (one 64-thread block per batch).
__global__ void __launch_bounds__(64)
setup_kernel(const float* __restrict__ f0,         // (B,T)
             const float* __restrict__ init_phase, // (B,80)
             const float* __restrict__ adsr,       // (B,T,4)
             const int*   __restrict__ note_on,    // (B,8)
             const int*   __restrict__ note_off,   // (B,8)
             double* __restrict__ S_rev,           // (B,T)
             float*  __restrict__ ip_rev,          // (B,80)
             float*  __restrict__ note_pre,        // (B,8,12)
             int T, int duration) {
    int b = blockIdx.x;
    int lane = threadIdx.x;               // 0..63
    int chunk = (T + 63) / 64;
    int start = lane * chunk;
    int end   = min(start + chunk, T);

    const float* f0b = f0 + (size_t)b * T;

    // ---- f64 exclusive scan of f0*0.01 across the wave ----
    double local = 0.0;
    for (int t = start; t < end; ++t) local += (double)f0b[t] * 0.01;

    double incl = local;
    for (int off = 1; off < 64; off <<= 1) {
        double n = __shfl_up(incl, off, 64);
        if (lane >= off) incl += n;
    }
    double run = incl - local;            // exclusive base for this lane

    double* Sb = S_rev + (size_t)b * T;
    for (int t = start; t < end; ++t) {
        Sb[t] = run;
        run += (double)f0b[t] * 0.01;
    }

    // ---- initial phase -> revolutions in [0,1) ----
    for (int h = lane; h < N_HARM; h += 64) {
        double x = (double)init_phase[b * N_HARM + h] * INV_TWO_PI_D;
        x -= floor(x);
        ip_rev[b * N_HARM + h] = (float)x;
    }

    // ---- ADSR per-note constants (lanes 0..7) ----
    if (lane < NUM_NOTES) {
        int n = lane;
        int on  = note_on [b * NUM_NOTES + n];
        int off = note_off[b * NUM_NOTES + n];
        int nsi = on * HOP;
        float ns_f, aend_f, dend_f, ne_f, rend_f, inv_a, c_dec, sus, s_rel;
        if (nsi >= 0 && nsi < duration) {
            int ne  = min(off * HOP, duration);
            int nfe = duration / HOP + 1;
            int onset = min(min(on, nfe - 1), T - 1);
            const float* p = adsr + ((size_t)b * T + onset) * 4;
            int a_n = (int)floor((double)p[0] * 24000.0);   // exact in f64
            int d_n = (int)floor((double)p[1] * 24000.0);
            sus = p[2];
            int r_n = (int)floor((double)p[3] * 24000.0);
            int a_end = min(nsi + a_n, duration);
            int d_end = min(a_end + d_n, duration);
            int r_end = min(ne + r_n, duration);
            ns_f   = (float)nsi;     // all < 2^23: exact in f32
            aend_f = (float)a_end;
            dend_f = (float)d_end;
            ne_f   = (float)ne;
            rend_f = (float)r_end;
            inv_a  = 1.0f / (float)max(a_n, 1);
            c_dec  = (1.0f - sus) / (float)max(d_n, 1);
            s_rel  = sus / (float)max(r_n, 1);
        } else {
            ns_f = aend_f = dend_f = ne_f = rend_f = -1.0f;  // empty ranges
            inv_a = c_dec = sus = s_rel = 0.0f;
        }
        float* q = note_pre + ((size_t)b * NUM_NOTES + n) * 12;
        q[0] = ns_f;  q[1] = aend_f; q[2]  = dend_f; q[3]  = ne_f;
        q[4] = rend_f; q[5] = inv_a; q[6]  = c_dec;  q[7]  = sus;
        q[8] = s_rel; q[9] = 0.0f;   q[10] = 0.0f;   q[11] = 0.0f;
    }
}

// Kernel 2: one thread per output sample (b, s). Inner-loop operands staged
// to LDS once per block. A 256-sample block has i0 in {i0_min..i0_min+2}
// (coord span 255*T/duration ~= 1.06 can cross two integer boundaries),
// i1 = i0+1 <= i0_min+3 -> stage NROWS=4 rows.
__global__ void __launch_bounds__(BLK)
synth_kernel(const float* __restrict__ f0,        // (B,T)
             const float* __restrict__ harm_amp,  // (B,T,80)
             const float* __restrict__ vmix,      // (B,T)
             const double* __restrict__ S_rev,    // (B,T)
             const float*  __restrict__ ip_rev,   // (B,80)
             const float*  __restrict__ note_pre, // (B,8,12)
             float* __restrict__ out,             // (B,duration)
             int T, int duration) {
    __shared__ __align__(16) float lds_amp[NROWS * N_HARM];
    __shared__ __align__(16) float lds_ip [N_HARM];
    __shared__ __align__(16) float lds_np [NUM_NOTES * 12];
    __shared__ float lds_vm[NROWS];

    const int tid = threadIdx.x;
    const int b = blockIdx.y;
    const int s = blockIdx.x * BLK + tid;
    const int s_base = blockIdx.x * BLK;
    const double Tdur = (double)T / (double)duration;

    // ---- block-uniform first row index ----
    double coordb = fmax(((double)s_base + 0.5) * Tdur - 0.5, 0.0);
    const int i0_min = (int)floor(coordb);

    // ---- stage: NROWS amp rows (clamped at T-1), ip, note constants, vmix ----
    for (int idx = tid; idx < NROWS * N_HARM; idx += BLK) {
        int r = idx / N_HARM, h = idx - r * N_HARM;
        lds_amp[idx] = harm_amp[((size_t)b * T + min(i0_min + r, T - 1)) * N_HARM + h];
    }
    if (tid < N_HARM)          lds_ip[tid] = ip_rev[b * N_HARM + tid];
    if (tid < NUM_NOTES * 12)  lds_np[tid] = note_pre[(size_t)b * NUM_NOTES * 12 + tid];
    if (tid < NROWS)           lds_vm[tid] = vmix[(size_t)b * T + min(i0_min + tid, T - 1)];
    __syncthreads();

    if (s >= duration) return;

    const float sf = (float)s;

    // ---- ADSR from LDS constants ----
    float env = 0.0f;
#pragma unroll
    for (int n = 0; n < NUM_NOTES; ++n) {
        const float4* c = (const float4*)(lds_np + n * 12);
        float4 c0 = c[0];   // ns, a_end, d_end, ne
        float4 c1 = c[1];   // r_end, inv_a, c_dec, sus
        float  sr = lds_np[n * 12 + 8];
        env = (sf >= c0.x && sf < c0.y) ? (sf - c0.x) * c1.y          : env;
        env = (sf >= c0.y && sf < c0.z) ? 1.0f - c1.z * (sf - c0.y)   : env;
        env = (sf >= c0.z && sf < c0.w) ? c1.w                        : env;
        env = (sf >= c0.w && sf < c1.x) ? c1.w - sr * (sf - c0.w)     : env;
    }

    // ---- linear-interp indices/weights (f64 coord; exact boundary behavior) ----
    double coord = fmax(((double)s + 0.5) * Tdur - 0.5, 0.0);
    int i0 = (int)floor(coord);
    int i1 = min(i0 + 1, T - 1);
    float w   = (float)(coord - (double)i0);
    float omw = 1.0f - w;
    // staged row r holds amp[min(i0_min+r, T-1)]; r0 = i0-i0_min <= 2,
    // r1 = i1-i0_min <= 3 (proof in header comment). min() guards OOB.
    int r0 = min(i0 - i0_min, NROWS - 1);
    int r1 = min(i1 - i0_min, NROWS - 1);

    // ---- per-sample phase base, revolutions mod 1, f64-accurate ----
    int frame = min(s / HOP, T - 1);
    const float f0v = f0[(size_t)b * T + frame];
    double p_rev = (double)f0v * ((double)s * (1.0 / 24000.0)) + S_rev[(size_t)b * T + frame];
    p_rev -= floor(p_rev);                       // [0,1), error ~1e-12
    const float psi = (float)p_rev;              // cast err ~6e-8 rev

    const float4* A04 = (const float4*)(lds_amp + r0 * N_HARM);
    const float4* A14 = (const float4*)(lds_amp + r1 * N_HARM);
    const float4* IP4 = (const float4*)lds_ip;

    // arg_h = fract(h*psi + ip[h]) in [0,1) revolutions; v_sin_f32 = sin(2*pi*x).
    float acc0 = 0.0f, acc1 = 0.0f, acc2 = 0.0f, acc3 = 0.0f;
#pragma unroll 4
    for (int q = 0; q < N_HARM / 4; ++q) {
        float4 a0 = A04[q];
        float4 a1 = A14[q];
        float4 ip = IP4[q];
        float hb = (float)(4 * q);
        float v0 = fract1(fmaf(hb + 1.0f, psi, ip.x));
        float v1 = fract1(fmaf(hb + 2.0f, psi, ip.y));
        float v2 = fract1(fmaf(hb + 3.0f, psi, ip.z));
        float v3 = fract1(fmaf(hb + 4.0f, psi, ip.w));
        float s0 = __builtin_amdgcn_sinf(v0);
        float s1 = __builtin_amdgcn_sinf(v1);
        float s2 = __builtin_amdgcn_sinf(v2);
        float s3 = __builtin_amdgcn_sinf(v3);
        float m0 = fmaf(a0.x, omw, a1.x * w);
        float m1 = fmaf(a0.y, omw, a1.y * w);
        float m2 = fmaf(a0.z, omw, a1.z * w);
        float m3 = fmaf(a0.w, omw, a1.w * w);
        acc0 = fmaf(s0, m0, acc0);
        acc1 = fmaf(s1, m1, acc1);
        acc2 = fmaf(s2, m2, acc2);
        acc3 = fmaf(s3, m3, acc3);
    }
    float acc = (acc0 + acc1) + (acc2 + acc3);

    float vmv = lds_vm[r0] * omw + lds_vm[r1] * w;
    out[(size_t)b * duration + s] = acc * env * vmv;
}

extern "C" void kernel_launch(void* const* d_in, const int* in_sizes, int n_in,
                              void* d_out, int out_size, void* d_ws, size_t ws_size,
                              hipStream_t stream) {
    const float* f0   = (const float*)d_in[0];
    const float* ha   = (const float*)d_in[1];
    const float* vm   = (const float*)d_in[2];
    const float* adsr = (const float*)d_in[3];
    const float* ip   = (const float*)d_in[4];
    const int*   non  = (const int*)d_in[5];
    const int*   noff = (const int*)d_in[6];

    int B = in_sizes[4] / N_HARM;      // initial_phase is (B, 80)
    int T = in_sizes[0] / B;           // f0 is (B, T)
    int duration = out_size / B;       // out is (B, duration)

    // workspace: S_rev (B*T f64) | ip_rev (B*80 f32) | note_pre (B*8*12 f32)
    double* S_rev  = (double*)d_ws;
    float*  ip_rev = (float*)((char*)d_ws + (size_t)B * T * sizeof(double));
    float*  npre   = ip_rev + (size_t)B * N_HARM;

    setup_kernel<<<dim3(B), dim3(64), 0, stream>>>(f0, ip, adsr, non, noff,
                                                   S_rev, ip_rev, npre, T, duration);

    dim3 grid((duration + BLK - 1) / BLK, B);
    synth_kernel<<<grid, dim3(BLK), 0, stream>>>(f0, ha, vm, S_rev, ip_rev, npre,
                                                 (float*)d_out, T, duration);
}